// Round 8
// baseline (157.191 us; speedup 1.0000x reference)
//
#include <hip/hip_runtime.h>
#include <hip/hip_bf16.h>

// EfficientSelfAttention (PVT-style), B=8, N=16384 (128x128), C=64, 1 head, SR=8.
// Round 8: attn de-scatter — x staged coalesced via LDS, qwp lane-coalesced,
// out written via LDS stage + coalesced float4. prep/convln otherwise as r7.
//
// ws layout (bytes):
//   wbp   512KB @0        conv weights bf16 permuted [kh][j][tc][g][n][i]
//   kbuf  256KB @524288   K bf16 [b][256][64]
//   vp    256KB @786432   V bf16 permuted [b][ks][g][ch][i]
//   qwp     8KB @1048576  q_w * scale, bf16, frag-ordered [tau][s][g][n][i]
//   pwp     8KB @1056768  proj_w bf16, permuted
//   qb_s   256B @1064960  q_b * scale, f32

typedef __attribute__((ext_vector_type(8))) short bf16x8;
typedef __attribute__((ext_vector_type(4))) float f32x4;

__device__ __forceinline__ unsigned short f2bf(float f) {
    union { __hip_bfloat16 h; unsigned short u; } cv;
    cv.h = __hip_bfloat16(f);
    return cv.u;
}
union U8 { uint4 u; bf16x8 v; };
__device__ __forceinline__ bf16x8 pack8(float e0,float e1,float e2,float e3,
                                        float e4,float e5,float e6,float e7){
    U8 r;
    r.u.x = (unsigned)f2bf(e0) | ((unsigned)f2bf(e1)<<16);
    r.u.y = (unsigned)f2bf(e2) | ((unsigned)f2bf(e3)<<16);
    r.u.z = (unsigned)f2bf(e4) | ((unsigned)f2bf(e5)<<16);
    r.u.w = (unsigned)f2bf(e6) | ((unsigned)f2bf(e7)<<16);
    return r.v;
}
__device__ __forceinline__ bf16x8 ldg8(const unsigned short* p){
    U8 r; r.u = *(const uint4*)p; return r.v;
}

// ---------------- kernel 0: weight permutes (LDS-staged, coalesced reads) ----
__global__ __launch_bounds__(256) void prep_kernel(
    const float* __restrict__ sr_w,
    const float* __restrict__ q_w, const float* __restrict__ q_b,
    const float* __restrict__ proj_w,
    unsigned short* __restrict__ wbp,
    unsigned short* __restrict__ qwp, unsigned short* __restrict__ pwp,
    float* __restrict__ qb_s)
{
    __shared__ float wsm[4096];          // one co-slice of sr_w, 16KB
    int co = blockIdx.x;
    int t  = threadIdx.x;
    #pragma unroll
    for (int u = 0; u < 4; ++u) {
        int e = (u*256 + t)*4;
        *(float4*)&wsm[e] = *(const float4*)(sr_w + (size_t)co*4096 + e);
    }
    __syncthreads();
    int tc = co >> 4, n = co & 15;
    #pragma unroll
    for (int u = 0; u < 2; ++u) {
        int gidx = t*2 + u;              // 0..511 = (kh, j, g)
        int g = gidx & 3, j = (gidx>>2) & 15, kh = gidx >> 6;
        int kw = j >> 1, cinb = (j&1)*32 + 8*g;
        float e[8];
        #pragma unroll
        for (int i = 0; i < 8; ++i)
            e[i] = wsm[(cinb + i)*64 + kh*8 + kw];
        U8 tmp; tmp.v = pack8(e[0],e[1],e[2],e[3],e[4],e[5],e[6],e[7]);
        *(uint4*)(wbp + (size_t)((((kh*16 + j)*4 + tc)*4 + g)*16 + n)*8) = tmp.u;
    }
    int tid = co*256 + t;                // 0..16383
    if (tid < 4096) { // qwp[(((tau*2+s)*4+g)*16+n2)*8+i] = qw[16tau+n2][32s+8g+i]*0.125
        int i = tid & 7, n2 = (tid>>3)&15, g = (tid>>7)&3, s = (tid>>9)&1, tau = tid>>10;
        qwp[tid] = f2bf(q_w[(16*tau + n2)*64 + 32*s + 8*g + i] * 0.125f);
    }
    if (tid < 4096) { // pwp[((co2*2+s3)*4+g)*8+i] = pw[co2][16*(2s3+(i>>2))+4g+(i&3)]
        int i = tid & 7, g = (tid>>3)&3, s3 = (tid>>5)&1, co2 = tid>>6;
        int ch = 32*s3 + 16*(i>>2) + 4*g + (i&3);
        pwp[tid] = f2bf(proj_w[co2*64 + ch]);
    }
    if (tid < 64) qb_s[tid] = q_b[tid] * 0.125f;
}

// ---------------- kernel 1: fused conv(8x8/8) + LayerNorm + KV proj ----------
// (identical to round 7)
__global__ __launch_bounds__(512) void convln_kernel(
    const float* __restrict__ x, const unsigned short* __restrict__ wbp,
    const float* __restrict__ sr_b,
    const float* __restrict__ ln_g, const float* __restrict__ ln_b,
    const float* __restrict__ kv_w, const float* __restrict__ kv_b,
    unsigned short* __restrict__ kbuf, unsigned short* __restrict__ vp)
{
    __shared__ char xsm[32768];
    int bid = blockIdx.x;
    int b = bid >> 6, oh = (bid >> 2) & 15, oq = bid & 3;
    int t = threadIdx.x;
    int w = t >> 6, lane = t & 63, g = lane >> 4, n = lane & 15;

    #pragma unroll
    for (int c2 = 0; c2 < 4; ++c2) {
        int eo = (c2*512 + t) * 8;
        int r = eo >> 11, inrow = eo & 2047;
        const float* src = x + ((size_t)((b*128 + oh*8 + r)*128 + oq*32))*64 + inrow;
        float4 v0 = *(const float4*)(src);
        float4 v1 = *(const float4*)(src + 4);
        U8 tmp; tmp.v = pack8(v0.x,v0.y,v0.z,v0.w,v1.x,v1.y,v1.z,v1.w);
        *(uint4*)(xsm + eo*2) = tmp.u;
    }
    __syncthreads();

    int pos = n & 3;
    f32x4 acc[4] = {{0,0,0,0},{0,0,0,0},{0,0,0,0},{0,0,0,0}};
    #pragma unroll
    for (int j = 0; j < 16; ++j) {
        int byte = ((w*32 + pos*8 + (j>>1))*64 + (j&1)*32 + 8*g) * 2;
        U8 Bx; Bx.u = *(const uint4*)(xsm + byte);
        #pragma unroll
        for (int tc = 0; tc < 4; ++tc) {
            bf16x8 A = ldg8(wbp + (size_t)((((w*16 + j)*4 + tc)*4 + g)*16 + n)*8);
            acc[tc] = __builtin_amdgcn_mfma_f32_16x16x32_bf16(A, Bx.v, acc[tc], 0, 0, 0);
        }
    }
    __syncthreads();

    float* red = (float*)xsm;
    float* ysp = (float*)(xsm + 8192);
    if (n < 4) {
        #pragma unroll
        for (int tc = 0; tc < 4; ++tc)
            *(f32x4*)(red + (w*4 + n)*64 + 16*tc + 4*g) = acc[tc];
    }
    __syncthreads();

    if (w < 4) {
        int p = w, c = lane;
        float val = sr_b[c];
        #pragma unroll
        for (int w8 = 0; w8 < 8; ++w8)
            val += red[(w8*4 + p)*64 + c];
        float s = val, s2 = val*val;
        #pragma unroll
        for (int o = 32; o >= 1; o >>= 1) {
            s  += __shfl_xor(s,  o, 64);
            s2 += __shfl_xor(s2, o, 64);
        }
        float mean = s * (1.f/64.f);
        float var  = s2 * (1.f/64.f) - mean*mean;
        float y = (val - mean) * rsqrtf(var + 1e-5f) * ln_g[c] + ln_b[c];
        ysp[p*64 + c] = y;
    }
    __syncthreads();
    if (w < 4) {
        int p = w, c = lane;
        int m = oh*16 + oq*4 + p;
        const float* yr = ysp + p*64;
        #pragma unroll
        for (int h = 0; h < 2; ++h) {
            int oc = c + h*64;
            float a2 = kv_b[oc];
            const float* wr = kv_w + oc*64;
            #pragma unroll
            for (int jj = 0; jj < 64; jj += 4) {
                float4 w4 = *(const float4*)(wr + jj);
                a2 += yr[jj]*w4.x + yr[jj+1]*w4.y + yr[jj+2]*w4.z + yr[jj+3]*w4.w;
            }
            if (h == 0) {
                kbuf[(b*256 + m)*64 + c] = f2bf(a2);
            } else {
                int ks2 = m >> 5, hi = (m >> 4) & 1, g2 = (m >> 2) & 3, r = m & 3;
                vp[(size_t)b*16384 + ((ks2*4 + g2)*64 + c)*8 + r + 4*hi] = f2bf(a2);
            }
        }
    }
}

// ---------------- kernel 2: fused attention, de-scattered I/O ----------------
// grid: b(8) x 128 row-tiles = 1024 blocks; 8 waves x 16 q-rows = 128 rows/block
// LDS: Xs [0,16K) x-block bf16 swz; Ks [16K,48K) K swz; Outs overlays Ks.
__global__ __launch_bounds__(512) void attn_kernel(
    const float* __restrict__ x,
    const unsigned short* __restrict__ qwp, const float* __restrict__ qb_s,
    const unsigned short* __restrict__ kbuf, const unsigned short* __restrict__ vp,
    const unsigned short* __restrict__ pwp, const float* __restrict__ proj_b,
    float* __restrict__ out)
{
    __shared__ char sm[49152];
    char* Xs = sm;                 // [128 rows][64 cols] bf16, swz by row
    char* Ks = sm + 16384;         // [256 rows][64 cols] bf16, swz by row
    char* Outs = sm + 16384;       // overlays Ks: [128 rows][64 co] f32, swz by row

    int bid = blockIdx.x;
    int b = bid >> 7, rt = bid & 127;
    int t = threadIdx.x;
    const size_t xelem = ((size_t)b*16384 + rt*128) * 64;

    // stage x-block (coalesced): 8192 f32 -> bf16
    #pragma unroll
    for (int c2 = 0; c2 < 4; ++c2) {
        int elem = (c2*512 + t)*4;
        int row = elem >> 6, col = elem & 63;
        float4 v = *(const float4*)(x + xelem + elem);
        unsigned lo = (unsigned)f2bf(v.x) | ((unsigned)f2bf(v.y)<<16);
        unsigned hi = (unsigned)f2bf(v.z) | ((unsigned)f2bf(v.w)<<16);
        uint2 pkt = make_uint2(lo, hi);
        *(uint2*)(Xs + ((row*128 + col*2) ^ ((row&7)<<4))) = pkt;
    }
    // stage K (coalesced)
    {
        const char* kb = (const char*)(kbuf + (size_t)b*16384);
        #pragma unroll
        for (int c = 0; c < 4; ++c) {
            int off = (c*512 + t) * 16;
            int dst = off ^ (((off >> 7) & 7) << 4);
            *(uint4*)(Ks + dst) = *(const uint4*)(kb + off);
        }
    }
    __syncthreads();

    int w = t >> 6, lane = t & 63, g = lane >> 4, n = lane & 15;
    int qrow = rt*128 + w*16 + n;
    int row16 = w*16 + n;
    const char* vpb = (const char*)(vp + (size_t)b*16384);

    // ---- q-proj: qT[co][q], x frags from Xs, weights lane-coalesced
    f32x4 qacc[4];
    #pragma unroll
    for (int tau = 0; tau < 4; ++tau)
        qacc[tau] = *(const f32x4*)(qb_s + 16*tau + 4*g);
    bf16x8 xq[2];
    #pragma unroll
    for (int s = 0; s < 2; ++s) {
        U8 X; X.u = *(const uint4*)(Xs + ((row16*128 + 64*s + 16*g) ^ ((n&7)<<4)));
        xq[s] = X.v;
    }
    #pragma unroll
    for (int tau = 0; tau < 4; ++tau)
        #pragma unroll
        for (int s = 0; s < 2; ++s) {
            bf16x8 A = ldg8(qwp + (((tau*2 + s)*4 + g)*16 + n)*8);
            qacc[tau] = __builtin_amdgcn_mfma_f32_16x16x32_bf16(A, xq[s], qacc[tau], 0,0,0);
        }
    bf16x8 qkB[2];
    #pragma unroll
    for (int s2 = 0; s2 < 2; ++s2)
        qkB[s2] = pack8(qacc[2*s2][0],  qacc[2*s2][1],  qacc[2*s2][2],  qacc[2*s2][3],
                        qacc[2*s2+1][0],qacc[2*s2+1][1],qacc[2*s2+1][2],qacc[2*s2+1][3]);

    // ---- QK^T (swapped): S^T[m][q]
    float S[16][4];
    #pragma unroll
    for (int tt = 0; tt < 16; ++tt) {
        f32x4 sa = {0.f, 0.f, 0.f, 0.f};
        int m = 16*tt + n;
        int base = m * 128;
        int swz = (m & 7) << 4;
        #pragma unroll
        for (int s2 = 0; s2 < 2; ++s2) {
            int c1 = (32*s2 + 4*g) * 2;
            uint2 d0 = *(const uint2*)(Ks + ((base + c1)      ^ swz));
            uint2 d1 = *(const uint2*)(Ks + ((base + c1 + 32) ^ swz));
            U8 A; A.u = make_uint4(d0.x, d0.y, d1.x, d1.y);
            sa = __builtin_amdgcn_mfma_f32_16x16x32_bf16(A.v, qkB[s2], sa, 0,0,0);
        }
        S[tt][0]=sa[0]; S[tt][1]=sa[1]; S[tt][2]=sa[2]; S[tt][3]=sa[3];
    }
    __syncthreads();               // Ks dead; Outs may be written after this

    // ---- softmax over m=256
    float rm[16];
    #pragma unroll
    for (int tt = 0; tt < 16; ++tt)
        rm[tt] = fmaxf(fmaxf(S[tt][0],S[tt][1]), fmaxf(S[tt][2],S[tt][3]));
    float m8[8];
    #pragma unroll
    for (int j = 0; j < 8; ++j) m8[j] = fmaxf(rm[2*j], rm[2*j+1]);
    float mx = fmaxf(fmaxf(fmaxf(m8[0],m8[1]),fmaxf(m8[2],m8[3])),
                     fmaxf(fmaxf(m8[4],m8[5]),fmaxf(m8[6],m8[7])));
    mx = fmaxf(mx, __shfl_xor(mx, 16, 64));
    mx = fmaxf(mx, __shfl_xor(mx, 32, 64));
    #pragma unroll
    for (int tt = 0; tt < 16; ++tt)
        #pragma unroll
        for (int r = 0; r < 4; ++r)
            S[tt][r] = __expf(S[tt][r] - mx);
    float rs[16];
    #pragma unroll
    for (int tt = 0; tt < 16; ++tt) rs[tt] = (S[tt][0]+S[tt][1]) + (S[tt][2]+S[tt][3]);
    float s8[8];
    #pragma unroll
    for (int j = 0; j < 8; ++j) s8[j] = rs[2*j] + rs[2*j+1];
    float ssum = ((s8[0]+s8[1])+(s8[2]+s8[3])) + ((s8[4]+s8[5])+(s8[6]+s8[7]));
    ssum += __shfl_xor(ssum, 16, 64);
    ssum += __shfl_xor(ssum, 32, 64);
    float inv = 1.f / ssum;        // deferred: applied after PV

    // ---- PV (V frags from L2, lane-coalesced)
    f32x4 oacc[4] = {{0,0,0,0},{0,0,0,0},{0,0,0,0},{0,0,0,0}};
    #pragma unroll
    for (int ks = 0; ks < 8; ++ks) {
        bf16x8 Bp = pack8(S[2*ks][0],  S[2*ks][1],  S[2*ks][2],  S[2*ks][3],
                          S[2*ks+1][0],S[2*ks+1][1],S[2*ks+1][2],S[2*ks+1][3]);
        #pragma unroll
        for (int tc = 0; tc < 4; ++tc) {
            U8 A; A.u = *(const uint4*)(vpb + ((ks*4 + g)*64 + 16*tc + n) * 16);
            oacc[tc] = __builtin_amdgcn_mfma_f32_16x16x32_bf16(A.v, Bp, oacc[tc], 0,0,0);
        }
    }

    // ---- out-proj
    bf16x8 Bo[2];
    #pragma unroll
    for (int s3 = 0; s3 < 2; ++s3)
        Bo[s3] = pack8(oacc[2*s3][0]*inv,   oacc[2*s3][1]*inv,
                       oacc[2*s3][2]*inv,   oacc[2*s3][3]*inv,
                       oacc[2*s3+1][0]*inv, oacc[2*s3+1][1]*inv,
                       oacc[2*s3+1][2]*inv, oacc[2*s3+1][3]*inv);
    f32x4 pacc[4];
    #pragma unroll
    for (int tf = 0; tf < 4; ++tf)
        pacc[tf] = *(const f32x4*)(proj_b + 16*tf + 4*g);
    #pragma unroll
    for (int tf = 0; tf < 4; ++tf)
        #pragma unroll
        for (int s3 = 0; s3 < 2; ++s3) {
            bf16x8 Aw = ldg8(pwp + (((16*tf + n)*2 + s3)*4 + g)*8);
            pacc[tf] = __builtin_amdgcn_mfma_f32_16x16x32_bf16(Aw, Bo[s3], pacc[tf], 0,0,0);
        }

    // dump to Outs (swz by row), then coalesced global write
    #pragma unroll
    for (int tf = 0; tf < 4; ++tf)
        *(f32x4*)(Outs + ((row16*256 + (16*tf + 4*g)*4) ^ ((n&7)<<4))) = pacc[tf];
    __syncthreads();
    #pragma unroll
    for (int u = 0; u < 4; ++u) {
        int elem = (u*512 + t)*4;
        int row = elem >> 6, col = elem & 63;
        f32x4 v = *(const f32x4*)(Outs + ((row*256 + col*4) ^ ((row&7)<<4)));
        *(float4*)(out + xelem + elem) = *(float4*)&v;
    }
}

extern "C" void kernel_launch(void* const* d_in, const int* in_sizes, int n_in,
                              void* d_out, int out_size, void* d_ws, size_t ws_size,
                              hipStream_t stream)
{
    const float* x      = (const float*)d_in[0];
    const float* sr_w   = (const float*)d_in[1];
    const float* sr_b   = (const float*)d_in[2];
    const float* ln_g   = (const float*)d_in[3];
    const float* ln_b   = (const float*)d_in[4];
    const float* q_w    = (const float*)d_in[5];
    const float* q_b    = (const float*)d_in[6];
    const float* kv_w   = (const float*)d_in[7];
    const float* kv_b   = (const float*)d_in[8];
    const float* proj_w = (const float*)d_in[9];
    const float* proj_b = (const float*)d_in[10];
    float* out = (float*)d_out;

    char* wsb = (char*)d_ws;
    unsigned short* wbp  = (unsigned short*)(wsb);            // 512KB
    unsigned short* kbuf = (unsigned short*)(wsb + 524288);   // 256KB
    unsigned short* vp   = (unsigned short*)(wsb + 786432);   // 256KB
    unsigned short* qwp  = (unsigned short*)(wsb + 1048576);  // 8KB
    unsigned short* pwp  = (unsigned short*)(wsb + 1056768);  // 8KB
    float*          qb_s = (float*)(wsb + 1064960);           // 256B

    hipLaunchKernelGGL(prep_kernel, dim3(64), dim3(256), 0, stream,
                       sr_w, q_w, q_b, proj_w, wbp, qwp, pwp, qb_s);
    hipLaunchKernelGGL(convln_kernel, dim3(512), dim3(512), 0, stream,
                       x, wbp, sr_b, ln_g, ln_b, kv_w, kv_b, kbuf, vp);
    hipLaunchKernelGGL(attn_kernel, dim3(1024), dim3(512), 0, stream,
                       x, qwp, qb_s, kbuf, vp, pwp, proj_b, out);
}

// Round 9
// 151.655 us; speedup vs baseline: 1.0365x; 1.0365x over previous
//
#include <hip/hip_runtime.h>
#include <hip/hip_bf16.h>

// EfficientSelfAttention (PVT-style), B=8, N=16384 (128x128), C=64, 1 head, SR=8.
// Round 9: attn restructure — K LDS layout channel-interleaved so each QK^T
// A-frag is one ds_read_b128 (was 4x ds_read_b64); 256-thread blocks (2048
// blocks, better overlap); XCD-chunked bid swizzle; setprio around MFMA.
// convln/prep frozen from round 8.
//
// ws layout (bytes):
//   wbp   512KB @0        conv weights bf16 permuted [kh][j][tc][g][n][i]
//   kbuf  256KB @524288   K bf16 [b][256][64]
//   vp    256KB @786432   V bf16 permuted [b][ks][g][ch][i]
//   qwp     8KB @1048576  q_w * scale, bf16, frag-ordered [tau][s][g][n][i]
//   pwp     8KB @1056768  proj_w bf16, permuted
//   qb_s   256B @1064960  q_b * scale, f32

typedef __attribute__((ext_vector_type(8))) short bf16x8;
typedef __attribute__((ext_vector_type(4))) float f32x4;

__device__ __forceinline__ unsigned short f2bf(float f) {
    union { __hip_bfloat16 h; unsigned short u; } cv;
    cv.h = __hip_bfloat16(f);
    return cv.u;
}
union U8 { uint4 u; bf16x8 v; };
__device__ __forceinline__ bf16x8 pack8(float e0,float e1,float e2,float e3,
                                        float e4,float e5,float e6,float e7){
    U8 r;
    r.u.x = (unsigned)f2bf(e0) | ((unsigned)f2bf(e1)<<16);
    r.u.y = (unsigned)f2bf(e2) | ((unsigned)f2bf(e3)<<16);
    r.u.z = (unsigned)f2bf(e4) | ((unsigned)f2bf(e5)<<16);
    r.u.w = (unsigned)f2bf(e6) | ((unsigned)f2bf(e7)<<16);
    return r.v;
}
__device__ __forceinline__ bf16x8 ldg8(const unsigned short* p){
    U8 r; r.u = *(const uint4*)p; return r.v;
}

// ---------------- kernel 0: weight permutes (identical to round 8) -----------
__global__ __launch_bounds__(256) void prep_kernel(
    const float* __restrict__ sr_w,
    const float* __restrict__ q_w, const float* __restrict__ q_b,
    const float* __restrict__ proj_w,
    unsigned short* __restrict__ wbp,
    unsigned short* __restrict__ qwp, unsigned short* __restrict__ pwp,
    float* __restrict__ qb_s)
{
    __shared__ float wsm[4096];
    int co = blockIdx.x;
    int t  = threadIdx.x;
    #pragma unroll
    for (int u = 0; u < 4; ++u) {
        int e = (u*256 + t)*4;
        *(float4*)&wsm[e] = *(const float4*)(sr_w + (size_t)co*4096 + e);
    }
    __syncthreads();
    int tc = co >> 4, n = co & 15;
    #pragma unroll
    for (int u = 0; u < 2; ++u) {
        int gidx = t*2 + u;
        int g = gidx & 3, j = (gidx>>2) & 15, kh = gidx >> 6;
        int kw = j >> 1, cinb = (j&1)*32 + 8*g;
        float e[8];
        #pragma unroll
        for (int i = 0; i < 8; ++i)
            e[i] = wsm[(cinb + i)*64 + kh*8 + kw];
        U8 tmp; tmp.v = pack8(e[0],e[1],e[2],e[3],e[4],e[5],e[6],e[7]);
        *(uint4*)(wbp + (size_t)((((kh*16 + j)*4 + tc)*4 + g)*16 + n)*8) = tmp.u;
    }
    int tid = co*256 + t;
    if (tid < 4096) {
        int i = tid & 7, n2 = (tid>>3)&15, g = (tid>>7)&3, s = (tid>>9)&1, tau = tid>>10;
        qwp[tid] = f2bf(q_w[(16*tau + n2)*64 + 32*s + 8*g + i] * 0.125f);
    }
    if (tid < 4096) {
        int i = tid & 7, g = (tid>>3)&3, s3 = (tid>>5)&1, co2 = tid>>6;
        int ch = 32*s3 + 16*(i>>2) + 4*g + (i&3);
        pwp[tid] = f2bf(proj_w[co2*64 + ch]);
    }
    if (tid < 64) qb_s[tid] = q_b[tid] * 0.125f;
}

// ---------------- kernel 1: fused conv + LN + KV (identical to round 8) ------
__global__ __launch_bounds__(512) void convln_kernel(
    const float* __restrict__ x, const unsigned short* __restrict__ wbp,
    const float* __restrict__ sr_b,
    const float* __restrict__ ln_g, const float* __restrict__ ln_b,
    const float* __restrict__ kv_w, const float* __restrict__ kv_b,
    unsigned short* __restrict__ kbuf, unsigned short* __restrict__ vp)
{
    __shared__ char xsm[32768];
    int bid = blockIdx.x;
    int b = bid >> 6, oh = (bid >> 2) & 15, oq = bid & 3;
    int t = threadIdx.x;
    int w = t >> 6, lane = t & 63, g = lane >> 4, n = lane & 15;

    #pragma unroll
    for (int c2 = 0; c2 < 4; ++c2) {
        int eo = (c2*512 + t) * 8;
        int r = eo >> 11, inrow = eo & 2047;
        const float* src = x + ((size_t)((b*128 + oh*8 + r)*128 + oq*32))*64 + inrow;
        float4 v0 = *(const float4*)(src);
        float4 v1 = *(const float4*)(src + 4);
        U8 tmp; tmp.v = pack8(v0.x,v0.y,v0.z,v0.w,v1.x,v1.y,v1.z,v1.w);
        *(uint4*)(xsm + eo*2) = tmp.u;
    }
    __syncthreads();

    int pos = n & 3;
    f32x4 acc[4] = {{0,0,0,0},{0,0,0,0},{0,0,0,0},{0,0,0,0}};
    #pragma unroll
    for (int j = 0; j < 16; ++j) {
        int byte = ((w*32 + pos*8 + (j>>1))*64 + (j&1)*32 + 8*g) * 2;
        U8 Bx; Bx.u = *(const uint4*)(xsm + byte);
        #pragma unroll
        for (int tc = 0; tc < 4; ++tc) {
            bf16x8 A = ldg8(wbp + (size_t)((((w*16 + j)*4 + tc)*4 + g)*16 + n)*8);
            acc[tc] = __builtin_amdgcn_mfma_f32_16x16x32_bf16(A, Bx.v, acc[tc], 0, 0, 0);
        }
    }
    __syncthreads();

    float* red = (float*)xsm;
    float* ysp = (float*)(xsm + 8192);
    if (n < 4) {
        #pragma unroll
        for (int tc = 0; tc < 4; ++tc)
            *(f32x4*)(red + (w*4 + n)*64 + 16*tc + 4*g) = acc[tc];
    }
    __syncthreads();

    if (w < 4) {
        int p = w, c = lane;
        float val = sr_b[c];
        #pragma unroll
        for (int w8 = 0; w8 < 8; ++w8)
            val += red[(w8*4 + p)*64 + c];
        float s = val, s2 = val*val;
        #pragma unroll
        for (int o = 32; o >= 1; o >>= 1) {
            s  += __shfl_xor(s,  o, 64);
            s2 += __shfl_xor(s2, o, 64);
        }
        float mean = s * (1.f/64.f);
        float var  = s2 * (1.f/64.f) - mean*mean;
        float y = (val - mean) * rsqrtf(var + 1e-5f) * ln_g[c] + ln_b[c];
        ysp[p*64 + c] = y;
    }
    __syncthreads();
    if (w < 4) {
        int p = w, c = lane;
        int m = oh*16 + oq*4 + p;
        const float* yr = ysp + p*64;
        #pragma unroll
        for (int h = 0; h < 2; ++h) {
            int oc = c + h*64;
            float a2 = kv_b[oc];
            const float* wr = kv_w + oc*64;
            #pragma unroll
            for (int jj = 0; jj < 64; jj += 4) {
                float4 w4 = *(const float4*)(wr + jj);
                a2 += yr[jj]*w4.x + yr[jj+1]*w4.y + yr[jj+2]*w4.z + yr[jj+3]*w4.w;
            }
            if (h == 0) {
                kbuf[(b*256 + m)*64 + c] = f2bf(a2);
            } else {
                int ks2 = m >> 5, hi = (m >> 4) & 1, g2 = (m >> 2) & 3, r = m & 3;
                vp[(size_t)b*16384 + ((ks2*4 + g2)*64 + c)*8 + r + 4*hi] = f2bf(a2);
            }
        }
    }
}

// ---------------- kernel 2: fused attention (b128 K-frags, 4 waves) ----------
// grid 2048 x 256 thr. XCD-chunked: data_bid = (bid&7)*256 + bid>>3.
// LDS Ks: per (m, s2) a 64B cell of channel-interleaved K; frag g = one uint4
// at index (m*8 + s2*4 + g) ^ (m&7)  [uint4 units].
__global__ __launch_bounds__(256) void attn_kernel(
    const float* __restrict__ x,
    const unsigned short* __restrict__ qwp, const float* __restrict__ qb_s,
    const unsigned short* __restrict__ kbuf, const unsigned short* __restrict__ vp,
    const unsigned short* __restrict__ pwp, const float* __restrict__ proj_b,
    float* __restrict__ out)
{
    __shared__ uint4 KsV[2048];          // 32KB
    int bid = blockIdx.x;
    int dbid = (bid & 7)*256 + (bid >> 3);
    int b = dbid >> 8, rt = dbid & 255;
    int t = threadIdx.x;

    // stage K with channel interleave: cell (m=t, s2): chunks g from two 8B pieces
    {
        const char* kb = (const char*)kbuf + (size_t)b*32768;
        int m = t;
        #pragma unroll
        for (int s2 = 0; s2 < 2; ++s2) {
            const uint4* src = (const uint4*)(kb + m*128 + s2*64);
            uint4 L0 = src[0], L1 = src[1], L2 = src[2], L3 = src[3];
            int base = m*8 + s2*4, sw = m & 7;
            KsV[(base + 0) ^ sw] = make_uint4(L0.x, L0.y, L2.x, L2.y);
            KsV[(base + 1) ^ sw] = make_uint4(L0.z, L0.w, L2.z, L2.w);
            KsV[(base + 2) ^ sw] = make_uint4(L1.x, L1.y, L3.x, L3.y);
            KsV[(base + 3) ^ sw] = make_uint4(L1.z, L1.w, L3.z, L3.w);
        }
    }
    __syncthreads();

    int w = t >> 6, lane = t & 63, g = lane >> 4, n = lane & 15;
    int qrow = rt*64 + w*16 + n;
    const float* xr = x + ((size_t)b*16384 + qrow) * 64;
    const char* vpb = (const char*)(vp + (size_t)b*16384);

    // ---- q-proj
    f32x4 qacc[4];
    #pragma unroll
    for (int tau = 0; tau < 4; ++tau)
        qacc[tau] = *(const f32x4*)(qb_s + 16*tau + 4*g);
    bf16x8 xq[2];
    #pragma unroll
    for (int s = 0; s < 2; ++s) {
        float4 v0 = *(const float4*)(xr + 32*s + 8*g);
        float4 v1 = *(const float4*)(xr + 32*s + 8*g + 4);
        xq[s] = pack8(v0.x,v0.y,v0.z,v0.w,v1.x,v1.y,v1.z,v1.w);
    }
    #pragma unroll
    for (int tau = 0; tau < 4; ++tau)
        #pragma unroll
        for (int s = 0; s < 2; ++s) {
            bf16x8 A = ldg8(qwp + (((tau*2 + s)*4 + g)*16 + n)*8);
            qacc[tau] = __builtin_amdgcn_mfma_f32_16x16x32_bf16(A, xq[s], qacc[tau], 0,0,0);
        }
    bf16x8 qkB[2];
    #pragma unroll
    for (int s2 = 0; s2 < 2; ++s2)
        qkB[s2] = pack8(qacc[2*s2][0],  qacc[2*s2][1],  qacc[2*s2][2],  qacc[2*s2][3],
                        qacc[2*s2+1][0],qacc[2*s2+1][1],qacc[2*s2+1][2],qacc[2*s2+1][3]);

    // ---- QK^T (swapped): S^T[m][q]; A-frag = one b128 from KsV
    float S[16][4];
    __builtin_amdgcn_s_setprio(1);
    #pragma unroll
    for (int tt = 0; tt < 16; ++tt) {
        f32x4 sa = {0.f, 0.f, 0.f, 0.f};
        int m = 16*tt + n;
        int base = m*8, sw = m & 7;
        #pragma unroll
        for (int s2 = 0; s2 < 2; ++s2) {
            U8 A; A.u = KsV[(base + s2*4 + g) ^ sw];
            sa = __builtin_amdgcn_mfma_f32_16x16x32_bf16(A.v, qkB[s2], sa, 0,0,0);
        }
        S[tt][0]=sa[0]; S[tt][1]=sa[1]; S[tt][2]=sa[2]; S[tt][3]=sa[3];
    }
    __builtin_amdgcn_s_setprio(0);

    // ---- softmax over m=256
    float rm[16];
    #pragma unroll
    for (int tt = 0; tt < 16; ++tt)
        rm[tt] = fmaxf(fmaxf(S[tt][0],S[tt][1]), fmaxf(S[tt][2],S[tt][3]));
    float m8[8];
    #pragma unroll
    for (int j = 0; j < 8; ++j) m8[j] = fmaxf(rm[2*j], rm[2*j+1]);
    float mx = fmaxf(fmaxf(fmaxf(m8[0],m8[1]),fmaxf(m8[2],m8[3])),
                     fmaxf(fmaxf(m8[4],m8[5]),fmaxf(m8[6],m8[7])));
    mx = fmaxf(mx, __shfl_xor(mx, 16, 64));
    mx = fmaxf(mx, __shfl_xor(mx, 32, 64));
    #pragma unroll
    for (int tt = 0; tt < 16; ++tt)
        #pragma unroll
        for (int r = 0; r < 4; ++r)
            S[tt][r] = __expf(S[tt][r] - mx);
    float rs[16];
    #pragma unroll
    for (int tt = 0; tt < 16; ++tt) rs[tt] = (S[tt][0]+S[tt][1]) + (S[tt][2]+S[tt][3]);
    float s8[8];
    #pragma unroll
    for (int j = 0; j < 8; ++j) s8[j] = rs[2*j] + rs[2*j+1];
    float ssum = ((s8[0]+s8[1])+(s8[2]+s8[3])) + ((s8[4]+s8[5])+(s8[6]+s8[7]));
    ssum += __shfl_xor(ssum, 16, 64);
    ssum += __shfl_xor(ssum, 32, 64);
    float inv = 1.f / ssum;        // deferred: applied after PV

    // ---- PV (V frags from L2, lane-coalesced)
    f32x4 oacc[4] = {{0,0,0,0},{0,0,0,0},{0,0,0,0},{0,0,0,0}};
    __builtin_amdgcn_s_setprio(1);
    #pragma unroll
    for (int ks = 0; ks < 8; ++ks) {
        bf16x8 Bp = pack8(S[2*ks][0],  S[2*ks][1],  S[2*ks][2],  S[2*ks][3],
                          S[2*ks+1][0],S[2*ks+1][1],S[2*ks+1][2],S[2*ks+1][3]);
        #pragma unroll
        for (int tc = 0; tc < 4; ++tc) {
            U8 A; A.u = *(const uint4*)(vpb + ((ks*4 + g)*64 + 16*tc + n) * 16);
            oacc[tc] = __builtin_amdgcn_mfma_f32_16x16x32_bf16(A.v, Bp, oacc[tc], 0,0,0);
        }
    }
    __builtin_amdgcn_s_setprio(0);

    // ---- out-proj
    bf16x8 Bo[2];
    #pragma unroll
    for (int s3 = 0; s3 < 2; ++s3)
        Bo[s3] = pack8(oacc[2*s3][0]*inv,   oacc[2*s3][1]*inv,
                       oacc[2*s3][2]*inv,   oacc[2*s3][3]*inv,
                       oacc[2*s3+1][0]*inv, oacc[2*s3+1][1]*inv,
                       oacc[2*s3+1][2]*inv, oacc[2*s3+1][3]*inv);
    f32x4 pacc[4];
    #pragma unroll
    for (int tf = 0; tf < 4; ++tf)
        pacc[tf] = *(const f32x4*)(proj_b + 16*tf + 4*g);
    #pragma unroll
    for (int tf = 0; tf < 4; ++tf)
        #pragma unroll
        for (int s3 = 0; s3 < 2; ++s3) {
            bf16x8 Aw = ldg8(pwp + (((16*tf + n)*2 + s3)*4 + g)*8);
            pacc[tf] = __builtin_amdgcn_mfma_f32_16x16x32_bf16(Aw, Bo[s3], pacc[tf], 0,0,0);
        }
    float* orow = out + ((size_t)b*16384 + qrow) * 64;
    #pragma unroll
    for (int tf = 0; tf < 4; ++tf)
        *(float4*)(orow + 16*tf + 4*g) = *(float4*)&pacc[tf];
}

extern "C" void kernel_launch(void* const* d_in, const int* in_sizes, int n_in,
                              void* d_out, int out_size, void* d_ws, size_t ws_size,
                              hipStream_t stream)
{
    const float* x      = (const float*)d_in[0];
    const float* sr_w   = (const float*)d_in[1];
    const float* sr_b   = (const float*)d_in[2];
    const float* ln_g   = (const float*)d_in[3];
    const float* ln_b   = (const float*)d_in[4];
    const float* q_w    = (const float*)d_in[5];
    const float* q_b    = (const float*)d_in[6];
    const float* kv_w   = (const float*)d_in[7];
    const float* kv_b   = (const float*)d_in[8];
    const float* proj_w = (const float*)d_in[9];
    const float* proj_b = (const float*)d_in[10];
    float* out = (float*)d_out;

    char* wsb = (char*)d_ws;
    unsigned short* wbp  = (unsigned short*)(wsb);            // 512KB
    unsigned short* kbuf = (unsigned short*)(wsb + 524288);   // 256KB
    unsigned short* vp   = (unsigned short*)(wsb + 786432);   // 256KB
    unsigned short* qwp  = (unsigned short*)(wsb + 1048576);  // 8KB
    unsigned short* pwp  = (unsigned short*)(wsb + 1056768);  // 8KB
    float*          qb_s = (float*)(wsb + 1064960);           // 256B

    hipLaunchKernelGGL(prep_kernel, dim3(64), dim3(256), 0, stream,
                       sr_w, q_w, q_b, proj_w, wbp, qwp, pwp, qb_s);
    hipLaunchKernelGGL(convln_kernel, dim3(512), dim3(512), 0, stream,
                       x, wbp, sr_b, ln_g, ln_b, kv_w, kv_b, kbuf, vp);
    hipLaunchKernelGGL(attn_kernel, dim3(2048), dim3(256), 0, stream,
                       x, qwp, qb_s, kbuf, vp, pwp, proj_b, out);
}